// Round 6
// baseline (620.754 us; speedup 1.0000x reference)
//
#include <hip/hip_runtime.h>

// ---------------------------------------------------------------------------
// LinformerAttention on MI355X (gfx950) — round 6.
// B=4, N=4096, C=1024, H=16, K_LM=256, d=64.
// vs round 5 (497 us):
//   * attn_fused: MFMA fragments loaded DIRECTLY from global (contraction dim
//     contiguous in Q/Klm/VlmT); P D->A transform via wave-private LDS rows
//     -> ZERO barriers, no staging round-trips.
//   * lm_gemm: same direct-global fragment loads -> barrier-free, no LDS.
//   * gemm_qkv / gemm_nt_128 unchanged (near m97 structural plateau).
// ---------------------------------------------------------------------------

typedef unsigned short ushort_t;
typedef float f32x4 __attribute__((ext_vector_type(4)));
typedef __bf16 bf16x8 __attribute__((ext_vector_type(8)));
typedef unsigned short ushort8 __attribute__((ext_vector_type(8)));
typedef unsigned short ushort4_t __attribute__((ext_vector_type(4)));

__device__ inline ushort_t f2bf(float f) {
  unsigned int u = __float_as_uint(f);
  u += 0x7fff + ((u >> 16) & 1);   // RNE
  return (ushort_t)(u >> 16);
}

// async global -> LDS, 16 B per lane. LDS dest is wave-uniform base + lane*16.
__device__ inline void gload_lds16(const ushort_t* g, ushort_t* l) {
  __builtin_amdgcn_global_load_lds(
      (const __attribute__((address_space(1))) void*)g,
      (__attribute__((address_space(3))) void*)l, 16, 0, 0);
}

// ------------------------- f32 -> bf16 convert -----------------------------
__global__ void cvt_f32_bf16(const float* __restrict__ in, ushort_t* __restrict__ out, int n4) {
  int i = blockIdx.x * blockDim.x + threadIdx.x;
  if (i < n4) {
    float4 v = ((const float4*)in)[i];
    ushort4_t o;
    o.x = f2bf(v.x); o.y = f2bf(v.y); o.z = f2bf(v.z); o.w = f2bf(v.w);
    ((ushort4_t*)out)[i] = o;
  }
}

// --------- fused QKV GEMM + repack:  qkv = x @ Wqkv^T, scatter to q/kT/vT --
// A = x_bf [16384][1024], W = wqkv_bf [3072][1024].  128x128 tile, BK=64 as
// two 32-wide panels; async global_load_lds staging, unpadded [128][32] panels.
__global__ __launch_bounds__(256) void gemm_qkv(
    const ushort_t* __restrict__ A, const ushort_t* __restrict__ W,
    ushort_t* __restrict__ q, ushort_t* __restrict__ kT, ushort_t* __restrict__ vT) {
  __shared__ __align__(16) ushort_t smem[17408];  // 34,816 B (T alias [128][136])
  const int tid = threadIdx.x, lane = tid & 63, w = tid >> 6;
  const int wm = w & 1, wn = w >> 1;
  const int l15 = lane & 15, quad = lane >> 4;
  const long long m0 = (long long)blockIdx.x * 128;
  const long long n0 = (long long)blockIdx.y * 128;
  const int K = 1024;

  const f32x4 zz = {0.f, 0.f, 0.f, 0.f};
  f32x4 acc[4][4];
#pragma unroll
  for (int i = 0; i < 4; i++)
#pragma unroll
    for (int j = 0; j < 4; j++) acc[i][j] = zz;

  const int lr = lane >> 2, lc = (lane & 3) * 8;
  const ushort_t* gA0 = A + (m0 + 32 * w + lr) * K + lc;
  const ushort_t* gB0 = W + (n0 + 32 * w + lr) * K + lc;
  ushort_t* lA0 = smem + 32 * w * 32;
  ushort_t* lB0 = smem + 8192 + 32 * w * 32;

  for (int k0 = 0; k0 < K; k0 += 64) {
    __syncthreads();
#pragma unroll
    for (int p = 0; p < 2; p++) {
#pragma unroll
      for (int j = 0; j < 2; j++) {
        gload_lds16(gA0 + k0 + 32 * p + 16 * j * K, lA0 + p * 4096 + j * 512);
        gload_lds16(gB0 + k0 + 32 * p + 16 * j * K, lB0 + p * 4096 + j * 512);
      }
    }
    __syncthreads();
#pragma unroll
    for (int p = 0; p < 2; p++) {
      bf16x8 af[4], bf[4];
#pragma unroll
      for (int i = 0; i < 4; i++)
        af[i] = *(const bf16x8*)(smem + p * 4096 + (wm * 64 + i * 16 + l15) * 32 + quad * 8);
#pragma unroll
      for (int j = 0; j < 4; j++)
        bf[j] = *(const bf16x8*)(smem + 8192 + p * 4096 + (wn * 64 + j * 16 + l15) * 32 + quad * 8);
#pragma unroll
      for (int i = 0; i < 4; i++)
#pragma unroll
        for (int j = 0; j < 4; j++)
          acc[i][j] = __builtin_amdgcn_mfma_f32_16x16x32_bf16(af[i], bf[j], acc[i][j], 0, 0, 0);
    }
  }

  const int b     = (int)(m0 >> 12);
  const int nrow0 = (int)(m0 & 4095);
  const int s     = (int)(n0 >> 10);          // 0:q 1:k 2:v
  const int h0    = (int)((n0 & 1023) >> 6);

  if (s == 0) {
#pragma unroll
    for (int i = 0; i < 4; i++)
#pragma unroll
      for (int j = 0; j < 4; j++) {
        int c  = wn * 64 + j * 16;
        int h  = h0 + (c >> 6);
        int dd = (c & 63) + l15;
        long long z = b * 16 + h;
        int nb = nrow0 + wm * 64 + i * 16 + quad * 4;
#pragma unroll
        for (int r = 0; r < 4; r++)
          q[z * 262144 + (long long)(nb + r) * 64 + dd] = f2bf(acc[i][j][r]);
      }
  } else {
    ushort_t (*T)[136] = (ushort_t(*)[136])smem;   // [128 col][136] = 34,816 B
    __syncthreads();
#pragma unroll
    for (int i = 0; i < 4; i++)
#pragma unroll
      for (int j = 0; j < 4; j++) {
        int c = wn * 64 + j * 16 + l15;
        int t = wm * 64 + i * 16 + quad * 4;
        ushort4_t o = {f2bf(acc[i][j][0]), f2bf(acc[i][j][1]),
                       f2bf(acc[i][j][2]), f2bf(acc[i][j][3])};
        *(ushort4_t*)(&T[c][t]) = o;
      }
    __syncthreads();
    ushort_t* KV = (s == 1) ? kT : vT;
#pragma unroll
    for (int it = 0; it < 8; it++) {
      int ch = it * 256 + tid;
      int cl = ch >> 4, tc = (ch & 15) * 8;
      ushort8 v = *(const ushort8*)(&T[cl][tc]);
      int h = h0 + (cl >> 6), dd = cl & 63;
      long long z = b * 16 + h;
      *(ushort8*)(KV + z * 262144 + (long long)dd * 4096 + nrow0 + tc) = v;
    }
  }
}

// ---- fused landmark partials: pK/pV[(z*4+s)*16384 + k*64 + d] -------------
//   = sum_{n in split s} E[h][k][n] * {kT,vT}[z][d][n]
// Barrier-free: all fragments loaded directly from global (n contiguous).
__global__ __launch_bounds__(256) void lm_gemm(
    const ushort_t* __restrict__ E, const ushort_t* __restrict__ kT,
    const ushort_t* __restrict__ vT, float* __restrict__ pK, float* __restrict__ pV) {
  const int tid = threadIdx.x, lane = tid & 63, w = tid >> 6;
  const int l15 = lane & 15, quad = lane >> 4;
  const int kt = blockIdx.x;       // k-tile 0..3
  const int s  = blockIdx.y;       // split 0..3
  const int z  = blockIdx.z;       // 0..63
  const int h  = z & 15;

  // lane's A-row (E landmark row) and per-j B-rows (kT/vT d-rows)
  const ushort_t* eRow = E  + ((long long)h * 256 + kt * 64 + w * 16 + l15) * 4096 + s * 1024 + quad * 8;
  const ushort_t* kRow0 = kT + ((long long)z * 64 + l15) * 4096 + s * 1024 + quad * 8;
  const ushort_t* vRow0 = vT + ((long long)z * 64 + l15) * 4096 + s * 1024 + quad * 8;

  const f32x4 zz = {0.f, 0.f, 0.f, 0.f};
  f32x4 aK[4], aV[4];
#pragma unroll
  for (int j = 0; j < 4; j++) { aK[j] = zz; aV[j] = zz; }

  for (int n = 0; n < 1024; n += 64) {
#pragma unroll
    for (int p = 0; p < 2; p++) {
      const int off = n + 32 * p;
      bf16x8 ef = *(const bf16x8*)(eRow + off);
#pragma unroll
      for (int j = 0; j < 4; j++) {
        bf16x8 kf = *(const bf16x8*)(kRow0 + (long long)j * 16 * 4096 + off);
        aK[j] = __builtin_amdgcn_mfma_f32_16x16x32_bf16(ef, kf, aK[j], 0, 0, 0);
        bf16x8 vf = *(const bf16x8*)(vRow0 + (long long)j * 16 * 4096 + off);
        aV[j] = __builtin_amdgcn_mfma_f32_16x16x32_bf16(ef, vf, aV[j], 0, 0, 0);
      }
    }
  }

  float* oK = pK + ((long long)(z * 4 + s) * 256 + kt * 64) * 64;
  float* oV = pV + ((long long)(z * 4 + s) * 256 + kt * 64) * 64;
#pragma unroll
  for (int j = 0; j < 4; j++)
#pragma unroll
    for (int r = 0; r < 4; r++) {
      int row = w * 16 + quad * 4 + r, col = j * 16 + l15;
      oK[row * 64 + col] = aK[j][r];
      oV[row * 64 + col] = aV[j][r];
    }
}

// ---- reduce 4 splits -> klm[z][k][d] bf16 and vlmT[z][d][k] bf16 ----------
__global__ __launch_bounds__(256) void lm_reduce(
    const float* __restrict__ pK, const float* __restrict__ pV,
    ushort_t* __restrict__ klm, ushort_t* __restrict__ vlmT) {
  __shared__ float Tv[64][68];
  const int tid = threadIdx.x;
  const int kt = blockIdx.x;   // 0..3
  const int z  = blockIdx.y;   // 0..63
  const long long base = (long long)z * 4 * 16384 + kt * 64 * 64;
  const int row = tid >> 2, c0 = (tid & 3) * 16;

  float sk[16];
#pragma unroll
  for (int g = 0; g < 4; g++) {
    f32x4 a = {0.f, 0.f, 0.f, 0.f};
#pragma unroll
    for (int s = 0; s < 4; s++)
      a += *(const f32x4*)(pK + base + (long long)s * 16384 + row * 64 + c0 + g * 4);
    sk[g * 4 + 0] = a[0]; sk[g * 4 + 1] = a[1]; sk[g * 4 + 2] = a[2]; sk[g * 4 + 3] = a[3];
  }
  {
    ushort_t* dst = klm + ((long long)z * 256 + kt * 64 + row) * 64 + c0;
    ushort8 o0, o1;
#pragma unroll
    for (int i = 0; i < 8; i++) { o0[i] = f2bf(sk[i]); o1[i] = f2bf(sk[8 + i]); }
    *(ushort8*)(dst) = o0;
    *(ushort8*)(dst + 8) = o1;
  }

#pragma unroll
  for (int g = 0; g < 4; g++) {
    f32x4 a = {0.f, 0.f, 0.f, 0.f};
#pragma unroll
    for (int s = 0; s < 4; s++)
      a += *(const f32x4*)(pV + base + (long long)s * 16384 + row * 64 + c0 + g * 4);
    *(f32x4*)(&Tv[row][c0 + g * 4]) = a;
  }
  __syncthreads();
  {
    ushort8 o0, o1;
#pragma unroll
    for (int i = 0; i < 8; i++) {
      o0[i] = f2bf(Tv[c0 + i][row]);
      o1[i] = f2bf(Tv[c0 + 8 + i][row]);
    }
    ushort_t* dst = vlmT + ((long long)z * 64 + row) * 256 + kt * 64 + c0;
    *(ushort8*)(dst) = o0;
    *(ushort8*)(dst + 8) = o1;
  }
}

// -------- fused flash-style: O = softmax(q@k_lm^T/8) @ v_lm  ---------------
// Q:[64][4096][64], Klm:[64][256][64], VlmT:[64][64][256], O:[64][4096][64]
// BARRIER-FREE: fragments direct from global; P round-trips through
// wave-private LDS rows (wave w writes+reads rows [16w,16w+16) only).
__global__ __launch_bounds__(256) void attn_fused(
    const ushort_t* __restrict__ Q, const ushort_t* __restrict__ Klm,
    const ushort_t* __restrict__ VlmT, ushort_t* __restrict__ O) {
  __shared__ __align__(16) ushort_t P[64][264];   // 33,792 B
  const int tid = threadIdx.x, lane = tid & 63, w = tid >> 6;
  const int l15 = lane & 15, quad = lane >> 4;
  const int z = blockIdx.z;
  const long long m0 = (long long)blockIdx.x * 64;
  const ushort_t* Qb = Q + (long long)z * 262144;
  const ushort_t* Kb = Klm + (long long)z * 16384;
  const ushort_t* Vb = VlmT + (long long)z * 16384;

  const f32x4 zz = {0.f, 0.f, 0.f, 0.f};
  f32x4 acc[16];
#pragma unroll
  for (int j = 0; j < 16; j++) acc[j] = zz;

  // ---- phase 1: scores S[16 rows/wave][256] via direct-global fragments ---
#pragma unroll
  for (int kt = 0; kt < 2; kt++) {
    bf16x8 af = *(const bf16x8*)(Qb + (m0 + w * 16 + l15) * 64 + kt * 32 + quad * 8);
#pragma unroll
    for (int j = 0; j < 16; j++) {
      bf16x8 bfj = *(const bf16x8*)(Kb + (j * 16 + l15) * 64 + kt * 32 + quad * 8);
      acc[j] = __builtin_amdgcn_mfma_f32_16x16x32_bf16(af, bfj, acc[j], 0, 0, 0);
    }
  }

  // ---- phase 2: softmax over 256 landmarks; P -> LDS (D-layout -> A-layout)
#pragma unroll
  for (int r = 0; r < 4; r++) {
    float x[16];
    float vmax = -1e30f;
#pragma unroll
    for (int j = 0; j < 16; j++) { x[j] = acc[j][r] * 0.125f; vmax = fmaxf(vmax, x[j]); }
#pragma unroll
    for (int m = 1; m < 16; m <<= 1) vmax = fmaxf(vmax, __shfl_xor(vmax, m, 64));
    float s = 0.f;
#pragma unroll
    for (int j = 0; j < 16; j++) { x[j] = __expf(x[j] - vmax); s += x[j]; }
#pragma unroll
    for (int m = 1; m < 16; m <<= 1) s += __shfl_xor(s, m, 64);
    float inv = 1.0f / s;
    int row = w * 16 + quad * 4 + r;
#pragma unroll
    for (int j = 0; j < 16; j++)
      P[row][j * 16 + l15] = f2bf(x[j] * inv);
  }
  // no barrier: wave w wrote rows [16w,16w+16) and reads only those below
  // (in-wave LDS ordering via lgkmcnt, compiler-inserted)

  // ---- phase 3: O[64][64] = P @ VlmT^T, VlmT fragments direct from global --
  f32x4 o_acc[4];
#pragma unroll
  for (int j = 0; j < 4; j++) o_acc[j] = zz;
#pragma unroll
  for (int kc = 0; kc < 8; kc++) {
    bf16x8 pf = *(const bf16x8*)(&P[w * 16 + l15][kc * 32 + quad * 8]);
#pragma unroll
    for (int j = 0; j < 4; j++) {
      bf16x8 vf = *(const bf16x8*)(Vb + (j * 16 + l15) * 256 + kc * 32 + quad * 8);
      o_acc[j] = __builtin_amdgcn_mfma_f32_16x16x32_bf16(pf, vf, o_acc[j], 0, 0, 0);
    }
  }

#pragma unroll
  for (int j = 0; j < 4; j++)
#pragma unroll
    for (int r = 0; r < 4; r++) {
      int row = w * 16 + quad * 4 + r;
      int col = j * 16 + l15;
      O[(long long)z * 262144 + (m0 + row) * 64 + col] = f2bf(o_acc[j][r]);
    }
}

// ------------------- 128x128 tile NT GEMM, f32 out (+bias) -----------------
// BK=64 as two 32-wide panels, async staging, 32 KB LDS.
__global__ __launch_bounds__(256) void gemm_nt_128(
    const ushort_t* __restrict__ A, const ushort_t* __restrict__ B,
    float* __restrict__ C, const float* __restrict__ bias,
    int M, int N, int K) {
  __shared__ __align__(16) ushort_t smem[16384];
  const int tid = threadIdx.x, lane = tid & 63, w = tid >> 6;
  const int wm = w & 1, wn = w >> 1;
  const int l15 = lane & 15, quad = lane >> 4;
  const long long m0 = (long long)blockIdx.x * 128;
  const long long n0 = (long long)blockIdx.y * 128;

  const f32x4 zz = {0.f, 0.f, 0.f, 0.f};
  f32x4 acc[4][4];
#pragma unroll
  for (int i = 0; i < 4; i++)
#pragma unroll
    for (int j = 0; j < 4; j++) acc[i][j] = zz;

  const int lr = lane >> 2, lc = (lane & 3) * 8;
  const ushort_t* gA0 = A + (m0 + 32 * w + lr) * K + lc;
  const ushort_t* gB0 = B + (n0 + 32 * w + lr) * K + lc;
  ushort_t* lA0 = smem + 32 * w * 32;
  ushort_t* lB0 = smem + 8192 + 32 * w * 32;

  for (int k0 = 0; k0 < K; k0 += 64) {
    __syncthreads();
#pragma unroll
    for (int p = 0; p < 2; p++) {
#pragma unroll
      for (int j = 0; j < 2; j++) {
        gload_lds16(gA0 + k0 + 32 * p + 16 * j * K, lA0 + p * 4096 + j * 512);
        gload_lds16(gB0 + k0 + 32 * p + 16 * j * K, lB0 + p * 4096 + j * 512);
      }
    }
    __syncthreads();
#pragma unroll
    for (int p = 0; p < 2; p++) {
      bf16x8 af[4], bf[4];
#pragma unroll
      for (int i = 0; i < 4; i++)
        af[i] = *(const bf16x8*)(smem + p * 4096 + (wm * 64 + i * 16 + l15) * 32 + quad * 8);
#pragma unroll
      for (int j = 0; j < 4; j++)
        bf[j] = *(const bf16x8*)(smem + 8192 + p * 4096 + (wn * 64 + j * 16 + l15) * 32 + quad * 8);
#pragma unroll
      for (int i = 0; i < 4; i++)
#pragma unroll
        for (int j = 0; j < 4; j++)
          acc[i][j] = __builtin_amdgcn_mfma_f32_16x16x32_bf16(af[i], bf[j], acc[i][j], 0, 0, 0);
    }
  }

#pragma unroll
  for (int i = 0; i < 4; i++)
#pragma unroll
    for (int j = 0; j < 4; j++) {
      long long row = m0 + wm * 64 + i * 16 + quad * 4;
      long long col = n0 + wn * 64 + j * 16 + l15;
      float bv = bias ? bias[col] : 0.0f;
#pragma unroll
      for (int r = 0; r < 4; r++)
        C[(row + r) * (long long)N + col] = acc[i][j][r] + bv;
    }
}

// ---------------------------------------------------------------------------
extern "C" void kernel_launch(void* const* d_in, const int* in_sizes, int n_in,
                              void* d_out, int out_size, void* d_ws, size_t ws_size,
                              hipStream_t stream) {
  const float* x     = (const float*)d_in[0];
  const float* Wqkv  = (const float*)d_in[1];
  const float* E     = (const float*)d_in[2];
  const float* Wproj = (const float*)d_in[3];
  const float* bproj = (const float*)d_in[4];
  float* out = (float*)d_out;

  char* ws = (char*)d_ws;
  ushort_t* x_bf     = (ushort_t*)(ws + 0);            // 32 MB; later pK/pV, then attn O
  float*    pK       = (float*)   (ws + 0);            // 16 MB (after gemm_qkv)
  float*    pV       = (float*)   (ws + 16777216);     // 16 MB
  ushort_t* wqkv_bf  = (ushort_t*)(ws + 33554432);     //  6 MB
  ushort_t* e_bf     = (ushort_t*)(ws + 39845888);     // 32 MB
  ushort_t* wproj_bf = (ushort_t*)(ws + 73400320);     //  2 MB
  ushort_t* q_bf     = (ushort_t*)(ws + 75497472);     // 32 MB
  ushort_t* kT       = (ushort_t*)(ws + 109051904);    // 32 MB
  ushort_t* vT       = (ushort_t*)(ws + 142606336);    // 32 MB
  ushort_t* klm      = (ushort_t*)(ws + 176160768);    //  2 MB
  ushort_t* vlmT     = (ushort_t*)(ws + 178257920);    //  2 MB
  // total: 180,355,072 bytes

  // 1) f32 -> bf16 converts
  cvt_f32_bf16<<<16384, 256, 0, stream>>>(x, x_bf, 4194304);
  cvt_f32_bf16<<<3072, 256, 0, stream>>>(Wqkv, wqkv_bf, 786432);
  cvt_f32_bf16<<<16384, 256, 0, stream>>>(E, e_bf, 4194304);
  cvt_f32_bf16<<<1024, 256, 0, stream>>>(Wproj, wproj_bf, 262144);

  // 2) fused QKV GEMM + repack -> q(n,d), kT(d,n), vT(d,n) bf16
  gemm_qkv<<<dim3(128, 24), 256, 0, stream>>>(x_bf, wqkv_bf, q_bf, kT, vT);

  // 3) landmark partials (both K and V), split-K over n: 4x4x64 = 1024 blocks
  lm_gemm<<<dim3(4, 4, 64), 256, 0, stream>>>(e_bf, kT, vT, pK, pV);

  // 4) reduce splits -> klm[z][k][d], vlmT[z][d][k]
  lm_reduce<<<dim3(4, 64), 256, 0, stream>>>(pK, pV, klm, vlmT);

  // 5) fused scores+softmax+PV -> attn_out (B,H,N,d) contiguous
  attn_fused<<<dim3(64, 1, 64), 256, 0, stream>>>(q_bf, klm, vlmT, x_bf);

  // 6) out = attn_out @ Wproj^T + bproj  [16384 x 1024] f32
  gemm_nt_128<<<dim3(128, 8), 256, 0, stream>>>(x_bf, wproj_bf, out, bproj, 16384, 1024, 1024);
}

// Round 7
// 492.472 us; speedup vs baseline: 1.2605x; 1.2605x over previous
//
#include <hip/hip_runtime.h>

// ---------------------------------------------------------------------------
// LinformerAttention on MI355X (gfx950) — round 7.
// B=4, N=4096, C=1024, H=16, K_LM=256, d=64.
// vs round 6 (620 us — REGRESSION): direct-global MFMA fragment loads in
// lm_gemm/attn_fused reverted to round-5 LDS-staged versions (497 us base).
// New: (a) 4 convert kernels fused into 1 (fewer dispatch drains);
//      (b) L2-locality block swizzle in gemm_qkv / gemm_nt_128
//          (16m x 8n groups, FETCH_SIZE 125 MB -> target ~70 MB).
// ---------------------------------------------------------------------------

typedef unsigned short ushort_t;
typedef float f32x4 __attribute__((ext_vector_type(4)));
typedef __bf16 bf16x8 __attribute__((ext_vector_type(8)));
typedef unsigned short ushort8 __attribute__((ext_vector_type(8)));
typedef unsigned short ushort4_t __attribute__((ext_vector_type(4)));

__device__ inline ushort_t f2bf(float f) {
  unsigned int u = __float_as_uint(f);
  u += 0x7fff + ((u >> 16) & 1);   // RNE
  return (ushort_t)(u >> 16);
}

// async global -> LDS, 16 B per lane. LDS dest is wave-uniform base + lane*16.
__device__ inline void gload_lds16(const ushort_t* g, ushort_t* l) {
  __builtin_amdgcn_global_load_lds(
      (const __attribute__((address_space(1))) void*)g,
      (__attribute__((address_space(3))) void*)l, 16, 0, 0);
}

// --------------- fused f32 -> bf16 convert of all four inputs --------------
__global__ __launch_bounds__(256) void cvt_all(
    const float* __restrict__ x,  ushort_t* __restrict__ xo,
    const float* __restrict__ w1, ushort_t* __restrict__ w1o,
    const float* __restrict__ e,  ushort_t* __restrict__ eo,
    const float* __restrict__ w2, ushort_t* __restrict__ w2o) {
  // float4 chunk counts: x 4194304 | Wqkv 786432 | E 4194304 | Wproj 262144
  int i = blockIdx.x * blockDim.x + threadIdx.x;
  const float* in; ushort_t* out; int idx;
  if (i < 4194304)               { in = x;  out = xo;  idx = i; }
  else if (i < 4980736)          { in = w1; out = w1o; idx = i - 4194304; }
  else if (i < 9175040)          { in = e;  out = eo;  idx = i - 4980736; }
  else                           { in = w2; out = w2o; idx = i - 9175040; }
  float4 v = ((const float4*)in)[idx];
  ushort4_t o;
  o.x = f2bf(v.x); o.y = f2bf(v.y); o.z = f2bf(v.z); o.w = f2bf(v.w);
  ((ushort4_t*)out)[idx] = o;
}

// L2-locality swizzle: 16 m-tiles x 8 n-tiles per group, gn fastest.
// tiles_m % 16 == 0, tiles_n % 8 == 0.
__device__ inline void swizzle_tiles(int tiles_n, int& mt, int& nt) {
  const int lin = blockIdx.y * gridDim.x + blockIdx.x;
  const int g = lin >> 7, r = lin & 127;
  const int ngrp = tiles_n >> 3;
  const int gn = g % ngrp, gm = g / ngrp;
  mt = gm * 16 + (r & 15);
  nt = gn * 8 + (r >> 4);
}

// --------- fused QKV GEMM + repack:  qkv = x @ Wqkv^T, scatter to q/kT/vT --
// A = x_bf [16384][1024], W = wqkv_bf [3072][1024].  128x128 tile, BK=64 as
// two 32-wide panels; async global_load_lds staging, unpadded [128][32] panels.
__global__ __launch_bounds__(256) void gemm_qkv(
    const ushort_t* __restrict__ A, const ushort_t* __restrict__ W,
    ushort_t* __restrict__ q, ushort_t* __restrict__ kT, ushort_t* __restrict__ vT) {
  __shared__ __align__(16) ushort_t smem[17408];  // 34,816 B (T alias [128][136])
  const int tid = threadIdx.x, lane = tid & 63, w = tid >> 6;
  const int wm = w & 1, wn = w >> 1;
  const int l15 = lane & 15, quad = lane >> 4;
  int mt, nt;
  swizzle_tiles(24, mt, nt);
  const long long m0 = (long long)mt * 128;
  const long long n0 = (long long)nt * 128;
  const int K = 1024;

  const f32x4 zz = {0.f, 0.f, 0.f, 0.f};
  f32x4 acc[4][4];
#pragma unroll
  for (int i = 0; i < 4; i++)
#pragma unroll
    for (int j = 0; j < 4; j++) acc[i][j] = zz;

  const int lr = lane >> 2, lc = (lane & 3) * 8;
  const ushort_t* gA0 = A + (m0 + 32 * w + lr) * K + lc;
  const ushort_t* gB0 = W + (n0 + 32 * w + lr) * K + lc;
  ushort_t* lA0 = smem + 32 * w * 32;
  ushort_t* lB0 = smem + 8192 + 32 * w * 32;

  for (int k0 = 0; k0 < K; k0 += 64) {
    __syncthreads();
#pragma unroll
    for (int p = 0; p < 2; p++) {
#pragma unroll
      for (int j = 0; j < 2; j++) {
        gload_lds16(gA0 + k0 + 32 * p + 16 * j * K, lA0 + p * 4096 + j * 512);
        gload_lds16(gB0 + k0 + 32 * p + 16 * j * K, lB0 + p * 4096 + j * 512);
      }
    }
    __syncthreads();
#pragma unroll
    for (int p = 0; p < 2; p++) {
      bf16x8 af[4], bf[4];
#pragma unroll
      for (int i = 0; i < 4; i++)
        af[i] = *(const bf16x8*)(smem + p * 4096 + (wm * 64 + i * 16 + l15) * 32 + quad * 8);
#pragma unroll
      for (int j = 0; j < 4; j++)
        bf[j] = *(const bf16x8*)(smem + 8192 + p * 4096 + (wn * 64 + j * 16 + l15) * 32 + quad * 8);
#pragma unroll
      for (int i = 0; i < 4; i++)
#pragma unroll
        for (int j = 0; j < 4; j++)
          acc[i][j] = __builtin_amdgcn_mfma_f32_16x16x32_bf16(af[i], bf[j], acc[i][j], 0, 0, 0);
    }
  }

  const int b     = (int)(m0 >> 12);
  const int nrow0 = (int)(m0 & 4095);
  const int s     = (int)(n0 >> 10);          // 0:q 1:k 2:v
  const int h0    = (int)((n0 & 1023) >> 6);

  if (s == 0) {
#pragma unroll
    for (int i = 0; i < 4; i++)
#pragma unroll
      for (int j = 0; j < 4; j++) {
        int c  = wn * 64 + j * 16;
        int h  = h0 + (c >> 6);
        int dd = (c & 63) + l15;
        long long z = b * 16 + h;
        int nb = nrow0 + wm * 64 + i * 16 + quad * 4;
#pragma unroll
        for (int r = 0; r < 4; r++)
          q[z * 262144 + (long long)(nb + r) * 64 + dd] = f2bf(acc[i][j][r]);
      }
  } else {
    ushort_t (*T)[136] = (ushort_t(*)[136])smem;   // [128 col][136] = 34,816 B
    __syncthreads();
#pragma unroll
    for (int i = 0; i < 4; i++)
#pragma unroll
      for (int j = 0; j < 4; j++) {
        int c = wn * 64 + j * 16 + l15;
        int t = wm * 64 + i * 16 + quad * 4;
        ushort4_t o = {f2bf(acc[i][j][0]), f2bf(acc[i][j][1]),
                       f2bf(acc[i][j][2]), f2bf(acc[i][j][3])};
        *(ushort4_t*)(&T[c][t]) = o;
      }
    __syncthreads();
    ushort_t* KV = (s == 1) ? kT : vT;
#pragma unroll
    for (int it = 0; it < 8; it++) {
      int ch = it * 256 + tid;
      int cl = ch >> 4, tc = (ch & 15) * 8;
      ushort8 v = *(const ushort8*)(&T[cl][tc]);
      int h = h0 + (cl >> 6), dd = cl & 63;
      long long z = b * 16 + h;
      *(ushort8*)(KV + z * 262144 + (long long)dd * 4096 + nrow0 + tc) = v;
    }
  }
}

// ---- fused landmark partials: pK/pV[(z*4+s)*16384 + k*64 + d] -------------
//   = sum_{n in split s} E[h][k][n] * {kT,vT}[z][d][n]  (round-5 LDS version)
__global__ __launch_bounds__(256) void lm_gemm(
    const ushort_t* __restrict__ E, const ushort_t* __restrict__ kT,
    const ushort_t* __restrict__ vT, float* __restrict__ pK, float* __restrict__ pV) {
  __shared__ __align__(16) ushort_t smem[12288];  // E:0,2048  K:4096,6144  V:8192,10240
  const int tid = threadIdx.x, lane = tid & 63, w = tid >> 6;
  const int l15 = lane & 15, quad = lane >> 4;
  const int kt = blockIdx.x;       // k-tile 0..3
  const int s  = blockIdx.y;       // split 0..3
  const int z  = blockIdx.z;       // 0..63
  const int h  = z & 15;
  const int lr = lane >> 2, lc = (lane & 3) * 8;

  const ushort_t* gE = E  + ((long long)h * 256 + kt * 64 + 16 * w + lr) * 4096 + s * 1024 + lc;
  const ushort_t* gK = kT + ((long long)z * 64 + 16 * w + lr) * 4096 + s * 1024 + lc;
  const ushort_t* gV = vT + ((long long)z * 64 + 16 * w + lr) * 4096 + s * 1024 + lc;
  ushort_t* lE = smem + 512 * w;
  ushort_t* lK = smem + 4096 + 512 * w;
  ushort_t* lV = smem + 8192 + 512 * w;

  const f32x4 zz = {0.f, 0.f, 0.f, 0.f};
  f32x4 aK[4], aV[4];
#pragma unroll
  for (int j = 0; j < 4; j++) { aK[j] = zz; aV[j] = zz; }

  for (int n = 0; n < 1024; n += 64) {
    __syncthreads();
#pragma unroll
    for (int p = 0; p < 2; p++) {
      gload_lds16(gE + n + 32 * p, lE + p * 2048);
      gload_lds16(gK + n + 32 * p, lK + p * 2048);
      gload_lds16(gV + n + 32 * p, lV + p * 2048);
    }
    __syncthreads();
#pragma unroll
    for (int p = 0; p < 2; p++) {
      bf16x8 ef = *(const bf16x8*)(smem + p * 2048 + (w * 16 + l15) * 32 + quad * 8);
#pragma unroll
      for (int j = 0; j < 4; j++) {
        bf16x8 kf = *(const bf16x8*)(smem + 4096 + p * 2048 + (j * 16 + l15) * 32 + quad * 8);
        aK[j] = __builtin_amdgcn_mfma_f32_16x16x32_bf16(ef, kf, aK[j], 0, 0, 0);
        bf16x8 vf = *(const bf16x8*)(smem + 8192 + p * 2048 + (j * 16 + l15) * 32 + quad * 8);
        aV[j] = __builtin_amdgcn_mfma_f32_16x16x32_bf16(ef, vf, aV[j], 0, 0, 0);
      }
    }
  }

  float* oK = pK + ((long long)(z * 4 + s) * 256 + kt * 64) * 64;
  float* oV = pV + ((long long)(z * 4 + s) * 256 + kt * 64) * 64;
#pragma unroll
  for (int j = 0; j < 4; j++)
#pragma unroll
    for (int r = 0; r < 4; r++) {
      int row = w * 16 + quad * 4 + r, col = j * 16 + l15;
      oK[row * 64 + col] = aK[j][r];
      oV[row * 64 + col] = aV[j][r];
    }
}

// ---- reduce 4 splits -> klm[z][k][d] bf16 and vlmT[z][d][k] bf16 ----------
__global__ __launch_bounds__(256) void lm_reduce(
    const float* __restrict__ pK, const float* __restrict__ pV,
    ushort_t* __restrict__ klm, ushort_t* __restrict__ vlmT) {
  __shared__ float Tv[64][68];
  const int tid = threadIdx.x;
  const int kt = blockIdx.x;   // 0..3
  const int z  = blockIdx.y;   // 0..63
  const long long base = (long long)z * 4 * 16384 + kt * 64 * 64;
  const int row = tid >> 2, c0 = (tid & 3) * 16;

  float sk[16];
#pragma unroll
  for (int g = 0; g < 4; g++) {
    f32x4 a = {0.f, 0.f, 0.f, 0.f};
#pragma unroll
    for (int s = 0; s < 4; s++)
      a += *(const f32x4*)(pK + base + (long long)s * 16384 + row * 64 + c0 + g * 4);
    sk[g * 4 + 0] = a[0]; sk[g * 4 + 1] = a[1]; sk[g * 4 + 2] = a[2]; sk[g * 4 + 3] = a[3];
  }
  {
    ushort_t* dst = klm + ((long long)z * 256 + kt * 64 + row) * 64 + c0;
    ushort8 o0, o1;
#pragma unroll
    for (int i = 0; i < 8; i++) { o0[i] = f2bf(sk[i]); o1[i] = f2bf(sk[8 + i]); }
    *(ushort8*)(dst) = o0;
    *(ushort8*)(dst + 8) = o1;
  }

#pragma unroll
  for (int g = 0; g < 4; g++) {
    f32x4 a = {0.f, 0.f, 0.f, 0.f};
#pragma unroll
    for (int s = 0; s < 4; s++)
      a += *(const f32x4*)(pV + base + (long long)s * 16384 + row * 64 + c0 + g * 4);
    *(f32x4*)(&Tv[row][c0 + g * 4]) = a;
  }
  __syncthreads();
  {
    ushort8 o0, o1;
#pragma unroll
    for (int i = 0; i < 8; i++) {
      o0[i] = f2bf(Tv[c0 + i][row]);
      o1[i] = f2bf(Tv[c0 + 8 + i][row]);
    }
    ushort_t* dst = vlmT + ((long long)z * 64 + row) * 256 + kt * 64 + c0;
    *(ushort8*)(dst) = o0;
    *(ushort8*)(dst + 8) = o1;
  }
}

// -------- fused flash-style: O = softmax(q@k_lm^T/8) @ v_lm  ---------------
// Round-5 LDS-staged version (known-good perf).
__global__ __launch_bounds__(256) void attn_fused(
    const ushort_t* __restrict__ Q, const ushort_t* __restrict__ Klm,
    const ushort_t* __restrict__ VlmT, ushort_t* __restrict__ O) {
  __shared__ __align__(16) ushort_t smem[16896];          // 33,792 B
  ushort_t (*As)[40]  = (ushort_t(*)[40])smem;            // [64][40]
  ushort_t (*Bs)[40]  = (ushort_t(*)[40])(smem + 2560);   // [256][40]
  ushort_t (*P)[264]  = (ushort_t(*)[264])smem;           // [64][264] (aliases)
  const int tid = threadIdx.x, lane = tid & 63, w = tid >> 6;
  const int l15 = lane & 15, quad = lane >> 4;
  const int z = blockIdx.z;
  const long long m0 = (long long)blockIdx.x * 64;
  const ushort_t* Qb = Q + (long long)z * 262144;
  const ushort_t* Kb = Klm + (long long)z * 16384;
  const ushort_t* Vb = VlmT + (long long)z * 16384;

  const f32x4 zz = {0.f, 0.f, 0.f, 0.f};
  f32x4 acc[16];
#pragma unroll
  for (int j = 0; j < 16; j++) acc[j] = zz;

  const int sr = tid >> 2, sc = (tid & 3) * 8;

  // ---- phase 1: scores S[64][256] in registers ----
  for (int kt = 0; kt < 2; kt++) {
    const int k0 = kt * 32;
    ushort8 av = *(const ushort8*)(Qb + (m0 + sr) * 64 + k0 + sc);
    ushort8 bv[4];
#pragma unroll
    for (int r = 0; r < 4; r++) {
      int c = r * 256 + tid;
      bv[r] = *(const ushort8*)(Kb + (c >> 2) * 64 + k0 + (c & 3) * 8);
    }
    __syncthreads();
    *(ushort8*)(&As[sr][sc]) = av;
#pragma unroll
    for (int r = 0; r < 4; r++) {
      int c = r * 256 + tid;
      *(ushort8*)(&Bs[c >> 2][(c & 3) * 8]) = bv[r];
    }
    __syncthreads();
    bf16x8 af = *(const bf16x8*)(&As[w * 16 + l15][quad * 8]);
#pragma unroll
    for (int j = 0; j < 16; j++) {
      bf16x8 bfj = *(const bf16x8*)(&Bs[j * 16 + l15][quad * 8]);
      acc[j] = __builtin_amdgcn_mfma_f32_16x16x32_bf16(af, bfj, acc[j], 0, 0, 0);
    }
  }

  // ---- phase 2: softmax over 256 landmarks, P -> LDS (D-layout -> A-layout)
  __syncthreads();
#pragma unroll
  for (int r = 0; r < 4; r++) {
    float x[16];
    float vmax = -1e30f;
#pragma unroll
    for (int j = 0; j < 16; j++) { x[j] = acc[j][r] * 0.125f; vmax = fmaxf(vmax, x[j]); }
#pragma unroll
    for (int m = 1; m < 16; m <<= 1) vmax = fmaxf(vmax, __shfl_xor(vmax, m, 64));
    float s = 0.f;
#pragma unroll
    for (int j = 0; j < 16; j++) { x[j] = __expf(x[j] - vmax); s += x[j]; }
#pragma unroll
    for (int m = 1; m < 16; m <<= 1) s += __shfl_xor(s, m, 64);
    float inv = 1.0f / s;
    int row = w * 16 + quad * 4 + r;
#pragma unroll
    for (int j = 0; j < 16; j++)
      P[row][j * 16 + l15] = f2bf(x[j] * inv);
  }
  __syncthreads();

  // ---- phase 3: O[64][64] = P @ VlmT^T ----
  f32x4 o_acc[4];
#pragma unroll
  for (int j = 0; j < 4; j++) o_acc[j] = zz;
#pragma unroll
  for (int kc = 0; kc < 8; kc++) {
    bf16x8 pf = *(const bf16x8*)(&P[w * 16 + l15][kc * 32 + quad * 8]);
#pragma unroll
    for (int j = 0; j < 4; j++) {
      bf16x8 vf = *(const bf16x8*)(Vb + (j * 16 + l15) * 256 + kc * 32 + quad * 8);
      o_acc[j] = __builtin_amdgcn_mfma_f32_16x16x32_bf16(pf, vf, o_acc[j], 0, 0, 0);
    }
  }

#pragma unroll
  for (int j = 0; j < 4; j++)
#pragma unroll
    for (int r = 0; r < 4; r++) {
      int row = w * 16 + quad * 4 + r;
      int col = j * 16 + l15;
      O[(long long)z * 262144 + (m0 + row) * 64 + col] = f2bf(o_acc[j][r]);
    }
}

// ------------------- 128x128 tile NT GEMM, f32 out (+bias) -----------------
// BK=64 as two 32-wide panels, async staging, swizzled block mapping.
__global__ __launch_bounds__(256) void gemm_nt_128(
    const ushort_t* __restrict__ A, const ushort_t* __restrict__ B,
    float* __restrict__ C, const float* __restrict__ bias,
    int M, int N, int K) {
  __shared__ __align__(16) ushort_t smem[16384];
  const int tid = threadIdx.x, lane = tid & 63, w = tid >> 6;
  const int wm = w & 1, wn = w >> 1;
  const int l15 = lane & 15, quad = lane >> 4;
  int mt, nt;
  swizzle_tiles(gridDim.y, mt, nt);
  const long long m0 = (long long)mt * 128;
  const long long n0 = (long long)nt * 128;

  const f32x4 zz = {0.f, 0.f, 0.f, 0.f};
  f32x4 acc[4][4];
#pragma unroll
  for (int i = 0; i < 4; i++)
#pragma unroll
    for (int j = 0; j < 4; j++) acc[i][j] = zz;

  const int lr = lane >> 2, lc = (lane & 3) * 8;
  const ushort_t* gA0 = A + (m0 + 32 * w + lr) * K + lc;
  const ushort_t* gB0 = B + (n0 + 32 * w + lr) * K + lc;
  ushort_t* lA0 = smem + 32 * w * 32;
  ushort_t* lB0 = smem + 8192 + 32 * w * 32;

  for (int k0 = 0; k0 < K; k0 += 64) {
    __syncthreads();
#pragma unroll
    for (int p = 0; p < 2; p++) {
#pragma unroll
      for (int j = 0; j < 2; j++) {
        gload_lds16(gA0 + k0 + 32 * p + 16 * j * K, lA0 + p * 4096 + j * 512);
        gload_lds16(gB0 + k0 + 32 * p + 16 * j * K, lB0 + p * 4096 + j * 512);
      }
    }
    __syncthreads();
#pragma unroll
    for (int p = 0; p < 2; p++) {
      bf16x8 af[4], bf[4];
#pragma unroll
      for (int i = 0; i < 4; i++)
        af[i] = *(const bf16x8*)(smem + p * 4096 + (wm * 64 + i * 16 + l15) * 32 + quad * 8);
#pragma unroll
      for (int j = 0; j < 4; j++)
        bf[j] = *(const bf16x8*)(smem + 8192 + p * 4096 + (wn * 64 + j * 16 + l15) * 32 + quad * 8);
#pragma unroll
      for (int i = 0; i < 4; i++)
#pragma unroll
        for (int j = 0; j < 4; j++)
          acc[i][j] = __builtin_amdgcn_mfma_f32_16x16x32_bf16(af[i], bf[j], acc[i][j], 0, 0, 0);
    }
  }

#pragma unroll
  for (int i = 0; i < 4; i++)
#pragma unroll
    for (int j = 0; j < 4; j++) {
      long long row = m0 + wm * 64 + i * 16 + quad * 4;
      long long col = n0 + wn * 64 + j * 16 + l15;
      float bv = bias ? bias[col] : 0.0f;
#pragma unroll
      for (int r = 0; r < 4; r++)
        C[(row + r) * (long long)N + col] = acc[i][j][r] + bv;
    }
}

// ---------------------------------------------------------------------------
extern "C" void kernel_launch(void* const* d_in, const int* in_sizes, int n_in,
                              void* d_out, int out_size, void* d_ws, size_t ws_size,
                              hipStream_t stream) {
  const float* x     = (const float*)d_in[0];
  const float* Wqkv  = (const float*)d_in[1];
  const float* E     = (const float*)d_in[2];
  const float* Wproj = (const float*)d_in[3];
  const float* bproj = (const float*)d_in[4];
  float* out = (float*)d_out;

  char* ws = (char*)d_ws;
  ushort_t* x_bf     = (ushort_t*)(ws + 0);            // 32 MB; later pK/pV, then attn O
  float*    pK       = (float*)   (ws + 0);            // 16 MB (after gemm_qkv)
  float*    pV       = (float*)   (ws + 16777216);     // 16 MB
  ushort_t* wqkv_bf  = (ushort_t*)(ws + 33554432);     //  6 MB
  ushort_t* e_bf     = (ushort_t*)(ws + 39845888);     // 32 MB
  ushort_t* wproj_bf = (ushort_t*)(ws + 73400320);     //  2 MB
  ushort_t* q_bf     = (ushort_t*)(ws + 75497472);     // 32 MB
  ushort_t* kT       = (ushort_t*)(ws + 109051904);    // 32 MB
  ushort_t* vT       = (ushort_t*)(ws + 142606336);    // 32 MB
  ushort_t* klm      = (ushort_t*)(ws + 176160768);    //  2 MB
  ushort_t* vlmT     = (ushort_t*)(ws + 178257920);    //  2 MB
  // total: 180,355,072 bytes

  // 1) fused f32 -> bf16 converts (one dispatch)
  cvt_all<<<36864, 256, 0, stream>>>(x, x_bf, Wqkv, wqkv_bf, E, e_bf, Wproj, wproj_bf);

  // 2) fused QKV GEMM + repack -> q(n,d), kT(d,n), vT(d,n) bf16
  gemm_qkv<<<dim3(128, 24), 256, 0, stream>>>(x_bf, wqkv_bf, q_bf, kT, vT);

  // 3) landmark partials (both K and V), split-K over n: 4x4x64 = 1024 blocks
  lm_gemm<<<dim3(4, 4, 64), 256, 0, stream>>>(e_bf, kT, vT, pK, pV);

  // 4) reduce splits -> klm[z][k][d], vlmT[z][d][k]
  lm_reduce<<<dim3(4, 64), 256, 0, stream>>>(pK, pV, klm, vlmT);

  // 5) fused scores+softmax+PV -> attn_out (B,H,N,d) contiguous
  attn_fused<<<dim3(64, 1, 64), 256, 0, stream>>>(q_bf, klm, vlmT, x_bf);

  // 6) out = attn_out @ Wproj^T + bproj  [16384 x 1024] f32
  gemm_nt_128<<<dim3(128, 8), 256, 0, stream>>>(x_bf, wproj_bf, out, bproj, 16384, 1024, 1024);
}